// Round 5
// baseline (97.068 us; speedup 1.0000x reference)
//
#include <hip/hip_runtime.h>
#include <hip/hip_bf16.h>

#define CDIM   64
#define HWDIM  4096
#define NCODES 1024
#define NELEM  8388608   // 32*64*64*64 = N*C
#define NBLOCK 4096      // vq_main grid: 131072 rows / 32 rows-per-wave

typedef short bf16x8 __attribute__((ext_vector_type(8)));
typedef float f32x4  __attribute__((ext_vector_type(4)));

__device__ __forceinline__ unsigned short f2bf(float f) {
    union { float f; unsigned u; } v; v.f = f;
    unsigned r = v.u + 0x7fffu + ((v.u >> 16) & 1u);   // round-to-nearest-even
    return (unsigned short)(r >> 16);
}
__device__ __forceinline__ unsigned asu(float f) {
    union { float f; unsigned u; } v; v.f = f; return v.u;
}
__device__ __forceinline__ float asf(unsigned u) {
    union { unsigned u; float f; } v; v.u = u; return v.f;
}

// Precompute bf16 codebook + (-0.5*||e_k||^2) bias (MFMA C-operand).
__global__ void vq_prep(const float* __restrict__ E,
                        unsigned short* __restrict__ Eb,
                        float* __restrict__ bias05) {
    int t = blockIdx.x * blockDim.x + threadIdx.x;   // one thread per code
    if (t < NCODES) {
        float s = 0.f;
        #pragma unroll 8
        for (int c = 0; c < CDIM; ++c) {
            float v = E[t * CDIM + c];
            Eb[t * CDIM + c] = f2bf(v);
            s = fmaf(v, v, s);
        }
        bias05[t] = -0.5f * s;
    }
}

// One wave (= one block) owns 32 rows x the FULL 1024-code codebook.
// 4096 waves -> 4 waves/SIMD for latency hiding. Depth-4 B prefetch.
// score = z.e - 0.5||e||^2 (bias in MFMA C-init); argmax over packed keys.
__global__ __launch_bounds__(64, 4)
void vq_main(const float* __restrict__ z,
             const float* __restrict__ E,
             const unsigned short* __restrict__ Eb,
             const float* __restrict__ bias05,
             float* __restrict__ out,
             float* __restrict__ partial) {
    const int lane = threadIdx.x;   // 0..63
    const int lrow = lane & 15;     // row/code-col within 16-tile
    const int lgrp = lane >> 4;     // k-group 0..3

    const int n0 = blockIdx.x * 32;    // wave's first flat row (b*4096 + hw)
    const int b  = n0 >> 12;
    const int hw = n0 & 4095;          // 32-aligned; +31 stays in batch
    const float* zb   = z   + (size_t)b * (CDIM * HWDIM);
    float*       outb = out + (size_t)b * (CDIM * HWDIM);

    // A fragments: tile t rows n0+16t..+15. lane holds A[lrow][k=32s+8g+j].
    float szz = 0.f;
    bf16x8 afrag[2][2];
    #pragma unroll
    for (int t = 0; t < 2; ++t)
        #pragma unroll
        for (int s = 0; s < 2; ++s)
            #pragma unroll
            for (int j = 0; j < 8; ++j) {
                int c = 32 * s + 8 * lgrp + j;
                float v = zb[c * HWDIM + hw + t * 16 + lrow];
                szz = fmaf(v, v, szz);
                afrag[t][s][j] = (short)f2bf(v);
            }

    // running packed keys (score with code idx in low 10 bits), argmax
    float run[2][4];
    #pragma unroll
    for (int t = 0; t < 2; ++t)
        #pragma unroll
        for (int r = 0; r < 4; ++r) run[t][r] = -3.0e38f;

    auto compute = [&](bf16x8 b0, bf16x8 b1, float bv, unsigned code) {
        f32x4 ci = {bv, bv, bv, bv};
        #pragma unroll
        for (int t = 0; t < 2; ++t) {
            f32x4 acc = __builtin_amdgcn_mfma_f32_16x16x32_bf16(afrag[t][0], b0, ci, 0, 0, 0);
            acc = __builtin_amdgcn_mfma_f32_16x16x32_bf16(afrag[t][1], b1, acc, 0, 0, 0);
            #pragma unroll
            for (int r = 0; r < 4; ++r) {
                float key = asf((asu(acc[r]) & 0xFFFFFC00u) | code); // v_and_or_b32
                run[t][r] = fmaxf(run[t][r], key);
            }
        }
    };

    // depth-4 software prefetch: 4 static register slots (no runtime-indexed
    // register arrays). Prefetch addresses wrap with &1023 (in-bounds, unused
    // values on the final iterations).
    bf16x8 cb00, cb01, cb10, cb11, cb20, cb21, cb30, cb31;
    float  bv0, bv1, bv2, bv3;
    {
        int c0 = lrow,           c1 = 16 + lrow;
        int c2 = 32 + lrow,      c3 = 48 + lrow;
        cb00 = *(const bf16x8*)(Eb + c0 * CDIM + 8 * lgrp);
        cb01 = *(const bf16x8*)(Eb + c0 * CDIM + 32 + 8 * lgrp);
        cb10 = *(const bf16x8*)(Eb + c1 * CDIM + 8 * lgrp);
        cb11 = *(const bf16x8*)(Eb + c1 * CDIM + 32 + 8 * lgrp);
        cb20 = *(const bf16x8*)(Eb + c2 * CDIM + 8 * lgrp);
        cb21 = *(const bf16x8*)(Eb + c2 * CDIM + 32 + 8 * lgrp);
        cb30 = *(const bf16x8*)(Eb + c3 * CDIM + 8 * lgrp);
        cb31 = *(const bf16x8*)(Eb + c3 * CDIM + 32 + 8 * lgrp);
        bv0 = bias05[c0]; bv1 = bias05[c1];
        bv2 = bias05[c2]; bv3 = bias05[c3];
    }

    for (int kt = 0; kt < 64; kt += 4) {
        {   // sub-step 0
            bf16x8 t0 = cb00, t1 = cb01; float tv = bv0;
            int pc = ((kt + 4) * 16 + lrow) & 1023;
            cb00 = *(const bf16x8*)(Eb + pc * CDIM + 8 * lgrp);
            cb01 = *(const bf16x8*)(Eb + pc * CDIM + 32 + 8 * lgrp);
            bv0  = bias05[pc];
            compute(t0, t1, tv, (unsigned)(kt * 16 + lrow));
        }
        {   // sub-step 1
            bf16x8 t0 = cb10, t1 = cb11; float tv = bv1;
            int pc = ((kt + 5) * 16 + lrow) & 1023;
            cb10 = *(const bf16x8*)(Eb + pc * CDIM + 8 * lgrp);
            cb11 = *(const bf16x8*)(Eb + pc * CDIM + 32 + 8 * lgrp);
            bv1  = bias05[pc];
            compute(t0, t1, tv, (unsigned)((kt + 1) * 16 + lrow));
        }
        {   // sub-step 2
            bf16x8 t0 = cb20, t1 = cb21; float tv = bv2;
            int pc = ((kt + 6) * 16 + lrow) & 1023;
            cb20 = *(const bf16x8*)(Eb + pc * CDIM + 8 * lgrp);
            cb21 = *(const bf16x8*)(Eb + pc * CDIM + 32 + 8 * lgrp);
            bv2  = bias05[pc];
            compute(t0, t1, tv, (unsigned)((kt + 2) * 16 + lrow));
        }
        {   // sub-step 3
            bf16x8 t0 = cb30, t1 = cb31; float tv = bv3;
            int pc = ((kt + 7) * 16 + lrow) & 1023;
            cb30 = *(const bf16x8*)(Eb + pc * CDIM + 8 * lgrp);
            cb31 = *(const bf16x8*)(Eb + pc * CDIM + 32 + 8 * lgrp);
            bv3  = bias05[pc];
            compute(t0, t1, tv, (unsigned)((kt + 3) * 16 + lrow));
        }
    }

    // reduce packed keys across the 16 code-columns (lrow lanes): pure max
    #pragma unroll
    for (int m = 1; m <= 8; m <<= 1)
        #pragma unroll
        for (int t = 0; t < 2; ++t)
            #pragma unroll
            for (int r = 0; r < 4; ++r)
                run[t][r] = fmaxf(run[t][r], __shfl_xor(run[t][r], m, 64));

    // publish per-row argmin code: lane group g holds rows 4g+r of each tile
    __shared__ int sidx[32];
    if (lrow == 0) {
        #pragma unroll
        for (int t = 0; t < 2; ++t)
            #pragma unroll
            for (int r = 0; r < 4; ++r)
                sidx[t * 16 + 4 * lgrp + r] = (int)(asu(run[t][r]) & 1023u);
    }
    __syncthreads();

    // epilogue: gather fp32 codebook rows, write transposed out
    #pragma unroll
    for (int t = 0; t < 2; ++t) {
        const int idxr = sidx[t * 16 + lrow];
        const f32x4* ep  = (const f32x4*)(E + idxr * CDIM      + 8 * lgrp);
        const f32x4* ep2 = (const f32x4*)(E + idxr * CDIM + 32 + 8 * lgrp);
        f32x4 qa = ep[0], qb = ep[1], qc = ep2[0], qd = ep2[1];
        float* ob = outb + hw + t * 16 + lrow;
        #pragma unroll
        for (int j = 0; j < 4; ++j) {
            ob[(8 * lgrp + j)          * HWDIM] = qa[j];
            ob[(8 * lgrp + 4 + j)      * HWDIM] = qb[j];
            ob[(32 + 8 * lgrp + j)     * HWDIM] = qc[j];
            ob[(32 + 8 * lgrp + 4 + j) * HWDIM] = qd[j];
        }
    }

    // loss partial: sum z^2 + sum over rows of d_min (= -2 * packed score)
    float dsum = 0.f;
    #pragma unroll
    for (int t = 0; t < 2; ++t)
        #pragma unroll
        for (int r = 0; r < 4; ++r) dsum += run[t][r];
    float contrib = szz + ((lrow == 0) ? (-2.f * dsum) : 0.f);
    #pragma unroll
    for (int m = 32; m >= 1; m >>= 1) contrib += __shfl_xor(contrib, m, 64);
    if (lane == 0) partial[blockIdx.x] = contrib;
}

__global__ void vq_fin(const float* __restrict__ partial,
                       float* __restrict__ out) {
    int lane = threadIdx.x;   // 64 threads
    float s = 0.f;
    for (int i = lane; i < NBLOCK; i += 64) s += partial[i];
    #pragma unroll
    for (int m = 32; m >= 1; m >>= 1) s += __shfl_xor(s, m, 64);
    if (lane == 0) out[NELEM] = 1.25f * s / (float)NELEM;
}

extern "C" void kernel_launch(void* const* d_in, const int* in_sizes, int n_in,
                              void* d_out, int out_size, void* d_ws, size_t ws_size,
                              hipStream_t stream) {
    const float* z = (const float*)d_in[0];
    const float* E = (const float*)d_in[1];
    float* out = (float*)d_out;

    unsigned short* Eb = (unsigned short*)d_ws;                    // 128 KB
    float* bias05      = (float*)((char*)d_ws + 131072);           // 4 KB
    float* partial     = (float*)((char*)d_ws + 131072 + 4096);    // 16 KB

    vq_prep<<<4, 256, 0, stream>>>(E, Eb, bias05);
    vq_main<<<NBLOCK, 64, 0, stream>>>(z, E, Eb, bias05, out, partial);
    vq_fin<<<1, 64, 0, stream>>>(partial, out);
}

// Round 6
// 55.682 us; speedup vs baseline: 1.7433x; 1.7433x over previous
//
#include <hip/hip_runtime.h>
#include <hip/hip_bf16.h>

#define CDIM   64
#define HWDIM  4096
#define NCODES 1024
#define NELEM  8388608   // 32*64*64*64 = N*C
#define NBLOCK 512       // vq_main grid: 131072 rows / 256 rows-per-block
#define NPART  2048      // NBLOCK * 4 waves

typedef short bf16x8 __attribute__((ext_vector_type(8)));
typedef float f32x4  __attribute__((ext_vector_type(4)));

__device__ __forceinline__ unsigned short f2bf(float f) {
    union { float f; unsigned u; } v; v.f = f;
    unsigned r = v.u + 0x7fffu + ((v.u >> 16) & 1u);   // round-to-nearest-even
    return (unsigned short)(r >> 16);
}
__device__ __forceinline__ unsigned asu(float f) {
    union { float f; unsigned u; } v; v.f = f; return v.u;
}
__device__ __forceinline__ float asf(unsigned u) {
    union { unsigned u; float f; } v; v.u = u; return v.f;
}

// Precompute bf16 codebook + (-0.5*||e_k||^2) bias (MFMA C-operand).
__global__ void vq_prep(const float* __restrict__ E,
                        unsigned short* __restrict__ Eb,
                        float* __restrict__ bias05) {
    int t = blockIdx.x * blockDim.x + threadIdx.x;   // one thread per code
    if (t < NCODES) {
        float s = 0.f;
        #pragma unroll 8
        for (int c = 0; c < CDIM; ++c) {
            float v = E[t * CDIM + c];
            Eb[t * CDIM + c] = f2bf(v);
            s = fmaf(v, v, s);
        }
        bias05[t] = -0.5f * s;
    }
}

// Block = 4 waves x 64 rows = 256 rows. Codebook staged through LDS in two
// 512-code halves (64 KB, XOR-swizzled per 16B chunk: slot ^= row&7 so the
// stride-128B ds_read_b128 pattern is conflict-minimal). Inner loop reads B
// from LDS only. score = z.e - 0.5||e||^2 (bias folded into MFMA C-init);
// argmax over packed keys (code idx in low 10 mantissa bits).
__global__ __launch_bounds__(256)
void vq_main(const float* __restrict__ z,
             const float* __restrict__ E,
             const unsigned short* __restrict__ Eb,
             const float* __restrict__ bias05,
             float* __restrict__ out,
             float* __restrict__ partial) {
    __shared__ unsigned short sEb[512 * CDIM];   // 64 KB, swizzled

    const int lane = threadIdx.x & 63;
    const int wave = threadIdx.x >> 6;   // 0..3
    const int lrow = lane & 15;          // row/code-col within 16-tile
    const int lgrp = lane >> 4;          // k-group 0..3

    const int n0 = blockIdx.x * 256 + wave * 64;  // wave's first flat row
    const int b  = n0 >> 12;
    const int hw = n0 & 4095;            // 64-aligned; +63 stays in batch
    const float* zb   = z   + (size_t)b * (CDIM * HWDIM);
    float*       outb = out + (size_t)b * (CDIM * HWDIM);

    // A fragments: tile t rows n0+16t..+15. lane holds A[lrow][k=32s+8g+j].
    float szz = 0.f;
    bf16x8 afrag[4][2];
    #pragma unroll
    for (int t = 0; t < 4; ++t)
        #pragma unroll
        for (int s = 0; s < 2; ++s)
            #pragma unroll
            for (int j = 0; j < 8; ++j) {
                int c = 32 * s + 8 * lgrp + j;
                float v = zb[c * HWDIM + hw + t * 16 + lrow];
                szz = fmaf(v, v, szz);
                afrag[t][s][j] = (short)f2bf(v);
            }

    // running packed keys (score with code idx in low 10 bits), argmax
    float run[4][4];
    #pragma unroll
    for (int t = 0; t < 4; ++t)
        #pragma unroll
        for (int r = 0; r < 4; ++r) run[t][r] = -3.0e38f;

    for (int half = 0; half < 2; ++half) {
        // ---- stage 512 codes (64 KB) into LDS, swizzled ----
        if (half) __syncthreads();   // all waves done reading previous half
        {
            const unsigned short* src = Eb + half * 512 * CDIM;
            #pragma unroll
            for (int i = 0; i < 16; ++i) {
                int cid = i * 256 + threadIdx.x;   // 16B chunk id, 0..4095
                int row = cid >> 3;
                int s   = cid & 7;                 // swizzled slot
                int c   = s ^ (row & 7);           // source chunk
                bf16x8 v = *(const bf16x8*)(src + row * CDIM + c * 8);
                *(bf16x8*)((char*)sEb + row * 128 + s * 16) = v;
            }
        }
        __syncthreads();

        const int cbase = half * 512;
        float bvCur = bias05[cbase + lrow];
        #pragma unroll 2
        for (int kt = 0; kt < 32; ++kt) {
            const int rowh = kt * 16 + lrow;
            float bvNext = bias05[cbase + (((kt + 1) & 31) * 16 + lrow)];
            const char* base = (const char*)sEb + rowh * 128;
            const int s0 = (lgrp ^ (rowh & 7)) * 16;
            bf16x8 b0 = *(const bf16x8*)(base + s0);
            bf16x8 b1 = *(const bf16x8*)(base + (s0 ^ 64));
            const unsigned code = (unsigned)(cbase + rowh);
            f32x4 ci = {bvCur, bvCur, bvCur, bvCur};
            #pragma unroll
            for (int t = 0; t < 4; ++t) {
                f32x4 acc = __builtin_amdgcn_mfma_f32_16x16x32_bf16(afrag[t][0], b0, ci, 0, 0, 0);
                acc = __builtin_amdgcn_mfma_f32_16x16x32_bf16(afrag[t][1], b1, acc, 0, 0, 0);
                #pragma unroll
                for (int r = 0; r < 4; ++r) {
                    float key = asf((asu(acc[r]) & 0xFFFFFC00u) | code); // v_and_or_b32
                    run[t][r] = fmaxf(run[t][r], key);
                }
            }
            bvCur = bvNext;
        }
    }

    // reduce packed keys across the 16 code-columns (lrow lanes): pure max
    #pragma unroll
    for (int m = 1; m <= 8; m <<= 1)
        #pragma unroll
        for (int t = 0; t < 4; ++t)
            #pragma unroll
            for (int r = 0; r < 4; ++r)
                run[t][r] = fmaxf(run[t][r], __shfl_xor(run[t][r], m, 64));

    // redistribute winners via shuffles (no LDS): lane (lrow,lgrp) holds rows
    // 4*lgrp+r of each tile; epilogue thread needs row lrow of each tile.
    int idxe[4];
    #pragma unroll
    for (int t = 0; t < 4; ++t) {
        const int src = (lrow >> 2) << 4;   // a lane whose lgrp == lrow>>2
        float g0 = __shfl(run[t][0], src, 64);
        float g1 = __shfl(run[t][1], src, 64);
        float g2 = __shfl(run[t][2], src, 64);
        float g3 = __shfl(run[t][3], src, 64);
        float sel = (lrow & 2) ? ((lrow & 1) ? g3 : g2)
                               : ((lrow & 1) ? g1 : g0);
        idxe[t] = (int)(asu(sel) & 1023u);
    }

    // epilogue: gather fp32 codebook rows, write transposed out
    #pragma unroll
    for (int t = 0; t < 4; ++t) {
        const int idxr = idxe[t];
        const f32x4* ep  = (const f32x4*)(E + idxr * CDIM      + 8 * lgrp);
        const f32x4* ep2 = (const f32x4*)(E + idxr * CDIM + 32 + 8 * lgrp);
        f32x4 qa = ep[0], qb = ep[1], qc = ep2[0], qd = ep2[1];
        float* ob = outb + hw + t * 16 + lrow;
        #pragma unroll
        for (int j = 0; j < 4; ++j) {
            ob[(8 * lgrp + j)          * HWDIM] = qa[j];
            ob[(8 * lgrp + 4 + j)      * HWDIM] = qb[j];
            ob[(32 + 8 * lgrp + j)     * HWDIM] = qc[j];
            ob[(32 + 8 * lgrp + 4 + j) * HWDIM] = qd[j];
        }
    }

    // loss partial: sum z^2 + sum over rows of d_min (= -2 * packed score)
    float dsum = 0.f;
    #pragma unroll
    for (int t = 0; t < 4; ++t)
        #pragma unroll
        for (int r = 0; r < 4; ++r) dsum += run[t][r];
    float contrib = szz + ((lrow == 0) ? (-2.f * dsum) : 0.f);
    #pragma unroll
    for (int m = 32; m >= 1; m >>= 1) contrib += __shfl_xor(contrib, m, 64);
    if (lane == 0) partial[blockIdx.x * 4 + wave] = contrib;
}

__global__ void vq_fin(const float* __restrict__ partial,
                       float* __restrict__ out) {
    int lane = threadIdx.x;   // 64 threads
    float s = 0.f;
    for (int i = lane; i < NPART; i += 64) s += partial[i];
    #pragma unroll
    for (int m = 32; m >= 1; m >>= 1) s += __shfl_xor(s, m, 64);
    if (lane == 0) out[NELEM] = 1.25f * s / (float)NELEM;
}

extern "C" void kernel_launch(void* const* d_in, const int* in_sizes, int n_in,
                              void* d_out, int out_size, void* d_ws, size_t ws_size,
                              hipStream_t stream) {
    const float* z = (const float*)d_in[0];
    const float* E = (const float*)d_in[1];
    float* out = (float*)d_out;

    unsigned short* Eb = (unsigned short*)d_ws;                    // 128 KB
    float* bias05      = (float*)((char*)d_ws + 131072);           // 4 KB
    float* partial     = (float*)((char*)d_ws + 131072 + 4096);    // 8 KB

    vq_prep<<<4, 256, 0, stream>>>(E, Eb, bias05);
    vq_main<<<NBLOCK, 256, 0, stream>>>(z, E, Eb, bias05, out, partial);
    vq_fin<<<1, 64, 0, stream>>>(partial, out);
}